// Round 24
// baseline (29.604 us; speedup 1.0000x reference)
//
#include <hip/hip_runtime.h>
#include <math.h>

#define BATCH   256
#define IN_F    2048
#define OUT_F   256
#define NCOL    2048    /* OUT_F*KD */
#define OSTRIDE 2304    /* IN_F + OUT_F */
#define LOG2E   1.4426950408889634f

typedef float    f32x4  __attribute__((ext_vector_type(4)));
typedef _Float16 h16x2  __attribute__((ext_vector_type(2)));
typedef __fp16   fp16x2 __attribute__((ext_vector_type(2)));
typedef unsigned short u16;
typedef unsigned int   u32;
typedef unsigned char  u8;
typedef long long      i64;

// ws layout:
//   [0, 1MB)   Mh f16 [256 o][256 j][8 k]
//   [16,20MB)  Wt fp8 tiled [nt(128)][kc(256)][n16(16)][8]      (4 MB)
//   [24,24.5M) Xb fp8 tiled [rt(16)][kc(256)][r16(16)][8]*log2e (0.5 MB)
#define WT_BASE   (16u << 20)
#define XB_BASE   (24u << 20)

__device__ __forceinline__ float exp2_fast(float x) {
#if __has_builtin(__builtin_amdgcn_exp2f)
    return __builtin_amdgcn_exp2f(x);
#else
    float r; asm("v_exp_f32 %0, %1" : "=v"(r) : "v"(x)); return r;
#endif
}

__device__ __forceinline__ float hsum_neg(h16x2 s) {
#if __has_builtin(__builtin_amdgcn_fdot2)
    const h16x2 n1 = {(_Float16)-1.0f, (_Float16)-1.0f};
    return __builtin_amdgcn_fdot2(s, n1, 0.0f, false);
#else
    return -((float)s[0] + (float)s[1]);
#endif
}

__device__ __forceinline__ float bperm(int srcLane, float v) {
    return __builtin_bit_cast(float,
        __builtin_amdgcn_ds_bpermute(srcLane * 4, __builtin_bit_cast(int, v)));
}

// pack 4 f32 -> 4 fp8 e4m3 (RNE, OCP on gfx950) in one u32
__device__ __forceinline__ u32 pk4_fp8(float a, float b, float c, float d) {
    u32 r;
    asm("v_cvt_pk_fp8_f32 %0, %1, %2" : "=v"(r) : "v"(a), "v"(b));
    asm("v_cvt_pk_fp8_f32 %0, %1, %2 op_sel:[0,0,1]" : "+v"(r) : "v"(c), "v"(d));
    return r;
}

// ---------------------------------------------------------------------------
// Prep (256 blocks):  [identical to R19 — measured best]
//   0..127   tconv -> Wt fp8, XCD-aligned with gemm consumers (C%8 == b%8)
//   128..255 xconv -> Xb fp8 (*log2e)
// ---------------------------------------------------------------------------
__global__ __launch_bounds__(256)
void k_prep(const float* __restrict__ X, const float* __restrict__ T,
            u8* __restrict__ Wt, u8* __restrict__ Xb) {
    const int b = blockIdx.x, t = threadIdx.x;
    if (b < 128) {
        const int c8 = b & 7;                  // XCD group
        const int kg = b >> 3;                 // 128-k group (0..15)
        const int p  = t & 127;                // col-pair index
        const int C  = c8 + 8 * (p >> 4);      // C-panel (C%8 == c8)
        const int n  = C * 32 + (p & 15) * 2;  // even column
        const int kh = (t >> 7) * 64;          // k-half within group
        const int nt = n >> 4, n16 = n & 15;
#pragma unroll
        for (int kc = 0; kc < 8; ++kc) {
            const int kb = kg * 128 + kh + kc * 8;
            float a0[8], a1[8];
#pragma unroll
            for (int r = 0; r < 8; ++r) {
                float2 v = *(const float2*)(T + (size_t)(kb + r) * NCOL + n);
                a0[r] = v.x;
                a1[r] = v.y;
            }
            uint2 p0 = {pk4_fp8(a0[0], a0[1], a0[2], a0[3]),
                        pk4_fp8(a0[4], a0[5], a0[6], a0[7])};
            uint2 p1 = {pk4_fp8(a1[0], a1[1], a1[2], a1[3]),
                        pk4_fp8(a1[4], a1[5], a1[6], a1[7])};
            u8* dst = Wt + ((size_t)(nt * 256 + (kb >> 3)) * 16 + n16) * 8;
            *(uint2*)dst       = p0;
            *(uint2*)(dst + 8) = p1;
        }
    } else {
        const int g   = b - 128;               // 0..127
        const int rt  = g >> 3;                // 0..15
        const int kcb = (g & 7) * 32;          // kc block (32 kc)
        const int r16 = t >> 4;                // 0..15
        const int kc  = kcb + (t & 15) * 2;    // kc pair
        const int row = rt * 16 + r16;
        const float* src = X + (size_t)row * IN_F + kc * 8;
        float v[16];
#pragma unroll
        for (int i = 0; i < 4; ++i)
            *(f32x4*)(v + i * 4) = *(const f32x4*)(src + i * 4);
        uint2 q0 = {pk4_fp8(v[0] * LOG2E, v[1] * LOG2E, v[2] * LOG2E, v[3] * LOG2E),
                    pk4_fp8(v[4] * LOG2E, v[5] * LOG2E, v[6] * LOG2E, v[7] * LOG2E)};
        uint2 q1 = {pk4_fp8(v[8] * LOG2E, v[9] * LOG2E, v[10] * LOG2E, v[11] * LOG2E),
                    pk4_fp8(v[12] * LOG2E, v[13] * LOG2E, v[14] * LOG2E, v[15] * LOG2E)};
        *(uint2*)(Xb + ((size_t)(rt * 256 + kc)     * 16 + r16) * 8) = q0;
        *(uint2*)(Xb + ((size_t)(rt * 256 + kc + 1) * 16 + r16) * 8) = q1;
    }
}

// ---------------------------------------------------------------------------
// MFMA GEMM fp8 (8-way in-block split-K). [R19 body] + zero-init of out's
// o_b region (512 B/block) so the split pair kernel can atomic-accumulate.
// ---------------------------------------------------------------------------
__global__ __launch_bounds__(512, 4)
void k_gemm(const u8* __restrict__ Xb, const u8* __restrict__ Wt,
            u16* __restrict__ Mh, float* __restrict__ out) {
    __shared__ float L[8][32][33];     // 33.8 KB
    const int t = threadIdx.x, l = t & 63, kcw = t >> 6;
    const int bid = blockIdx.x;
    const int R = bid >> 6;            // 0..7
    const int C = bid & 63;            // 0..63

    // zero the o_b accumulation region (pair atomically adds into it)
    if (t < 128) {
        const int f = bid * 128 + t;   // 0..65535
        out[(size_t)(f >> 8) * OSTRIDE + IN_F + (f & 255)] = 0.f;
    }

    const int lo = (l >> 4) * 128 + (l & 15) * 8;   // bytes
    const u8* ap0 = Xb + (size_t)(R * 2) * 32768 + kcw * 4096 + lo;
    const u8* ap1 = ap0 + 32768;
    const u8* bp0 = Wt + (size_t)(C * 2) * 32768 + kcw * 4096 + lo;
    const u8* bp1 = bp0 + 32768;

    f32x4 c00 = {0.f,0.f,0.f,0.f}, c01 = {0.f,0.f,0.f,0.f};
    f32x4 c10 = {0.f,0.f,0.f,0.f}, c11 = {0.f,0.f,0.f,0.f};

#pragma unroll 8
    for (int s = 0; s < 8; ++s) {
        i64 a0 = *(const i64*)(ap0 + s * 512);
        i64 a1 = *(const i64*)(ap1 + s * 512);
        i64 b0 = *(const i64*)(bp0 + s * 512);
        i64 b1 = *(const i64*)(bp1 + s * 512);
        c00 = __builtin_amdgcn_mfma_f32_16x16x32_fp8_fp8(a0, b0, c00, 0, 0, 0);
        c01 = __builtin_amdgcn_mfma_f32_16x16x32_fp8_fp8(a0, b1, c01, 0, 0, 0);
        c10 = __builtin_amdgcn_mfma_f32_16x16x32_fp8_fp8(a1, b0, c10, 0, 0, 0);
        c11 = __builtin_amdgcn_mfma_f32_16x16x32_fp8_fp8(a1, b1, c11, 0, 0, 0);
    }

    const int lq = l >> 4, lm = l & 15;
#define PUT(acc, qi, qj) do { \
        _Pragma("unroll") \
        for (int r = 0; r < 4; ++r) \
            L[kcw][(qj) * 16 + lm][(qi) * 16 + lq * 4 + r] = acc[r]; \
    } while (0)
    PUT(c00, 0, 0); PUT(c01, 0, 1); PUT(c10, 1, 0); PUT(c11, 1, 1);
#undef PUT
    __syncthreads();

    if (t < 256) {
        const int o2 = t >> 6;             // 0..3
        const int jl = (t & 63) >> 1;      // 0..31
        const int k0 = (t & 1) * 4;        // 0 or 4
        float v[4];
#pragma unroll
        for (int i = 0; i < 4; ++i) {
            const int c = o2 * 8 + k0 + i;
            float s0 = (L[0][c][jl] + L[1][c][jl]) + (L[2][c][jl] + L[3][c][jl]);
            float s1 = (L[4][c][jl] + L[5][c][jl]) + (L[6][c][jl] + L[7][c][jl]);
            v[i] = s0 + s1;
        }
        fp16x2 p0 = __builtin_amdgcn_cvt_pkrtz(v[0], v[1]);
        fp16x2 p1 = __builtin_amdgcn_cvt_pkrtz(v[2], v[3]);
        uint2 pk = {__builtin_bit_cast(u32, p0), __builtin_bit_cast(u32, p1)};
        *(uint2*)(Mh + ((size_t)(C * 4 + o2) * 256 + R * 32 + jl) * 8 + k0) = pk;
    }
}

// ---------------------------------------------------------------------------
// Pairwise L1-exp2 v6: symmetric circulant split into d-range half-blocks.
// 512 blocks x 512 threads (2/CU): block (o, dh) handles d in
// [64*dh+1, 64*dh+64] with (jg = t&63, q = t>>6 -> 8 d each). Same per-pair
// math and credit algebra as v4.1. Halves combine via atomicAdd into out —
// exactly 2 commutative adds per output (bit-deterministic); gemm pre-zeros
// the region. x->out copy split across half-blocks.
// ---------------------------------------------------------------------------
__global__ __launch_bounds__(512)
void k_pair(const u16* __restrict__ Mh, const float* __restrict__ X,
            float* __restrict__ out) {
    __shared__ __align__(16) uint4 Msh[BATCH];    // 4 KB
    __shared__ float Ps[8][256];                  // 8 KB
    const int t = threadIdx.x;
    const int bid = blockIdx.x;
    const int po = bid >> 1, dh = bid & 1;
    const int g = po & 7, idx = po >> 3;
    const int o = (g + 8 * (idx >> 2)) * 4 + (idx & 3);   // (o>>2)%8 == g

    if (t < 256) Msh[t] = ((const uint4*)(Mh + (size_t)o * 2048))[t];

    {   // fused copy: row = po, this half-block copies columns [1024*dh, +1024)
        *(float2*)(out + (size_t)po * OSTRIDE + dh * 1024 + t * 2) =
            *(const float2*)(X + (size_t)po * IN_F + dh * 1024 + t * 2);
    }
    __syncthreads();

    const int jg = t & 63, q = t >> 6;            // q = 0..7
    h16x2 m[4][4];
#pragma unroll
    for (int c = 0; c < 4; ++c) {
        uint4 mm = Msh[jg + 64 * c];
        m[c][0] = __builtin_bit_cast(h16x2, mm.x);
        m[c][1] = __builtin_bit_cast(h16x2, mm.y);
        m[c][2] = __builtin_bit_cast(h16x2, mm.z);
        m[c][3] = __builtin_bit_cast(h16x2, mm.w);
    }

    float acc[4] = {0.f, 0.f, 0.f, 0.f};
    const int dbase = dh * 64 + q * 8 + 1;        // d in [64dh+1, 64dh+64]
#pragma unroll
    for (int ii = 0; ii < 8; ++ii) {
        const int d  = dbase + ii;
        const int dd = d & 63;
        const int dl = d >> 6;
        float e[4];
#pragma unroll
        for (int c = 0; c < 4; ++c) {
            uint4 uu = Msh[(jg + 64 * c + d) & 255];
            h16x2 d0 = __builtin_bit_cast(h16x2, uu.x) - m[c][0];
            h16x2 d1 = __builtin_bit_cast(h16x2, uu.y) - m[c][1];
            h16x2 d2 = __builtin_bit_cast(h16x2, uu.z) - m[c][2];
            h16x2 d3 = __builtin_bit_cast(h16x2, uu.w) - m[c][3];
            h16x2 e0 = __builtin_bit_cast(h16x2, __builtin_bit_cast(u32, d0) & 0x7fff7fffu);
            h16x2 e1 = __builtin_bit_cast(h16x2, __builtin_bit_cast(u32, d1) & 0x7fff7fffu);
            h16x2 e2 = __builtin_bit_cast(h16x2, __builtin_bit_cast(u32, d2) & 0x7fff7fffu);
            h16x2 e3 = __builtin_bit_cast(h16x2, __builtin_bit_cast(u32, d3) & 0x7fff7fffu);
            h16x2 s = (e0 + e1) + (e2 + e3);
            float ev = exp2_fast(hsum_neg(s));
            e[c] = ev;
            acc[c] += ev;
        }
        if (d != 128) {                           // wave-uniform branch
            const int src = (jg - dd) & 63;
            float r0 = bperm(src, e[0]);
            float r1 = bperm(src, e[1]);
            float r2 = bperm(src, e[2]);
            float r3 = bperm(src, e[3]);
            const int rot = dl + (jg < dd ? 1 : 0);   // 0..2
            acc[0] += rot == 0 ? r0 : (rot == 1 ? r3 : r2);
            acc[1] += rot == 0 ? r1 : (rot == 1 ? r0 : r3);
            acc[2] += rot == 0 ? r2 : (rot == 1 ? r1 : r0);
            acc[3] += rot == 0 ? r3 : (rot == 1 ? r2 : r1);
        }
    }
#pragma unroll
    for (int c = 0; c < 4; ++c) Ps[q][jg + 64 * c] = acc[c];
    __syncthreads();

    if (t < 256) {
        float s = 0.f;
#pragma unroll
        for (int q2 = 0; q2 < 8; ++q2) s += Ps[q2][t];
        atomicAdd(out + (size_t)t * OSTRIDE + IN_F + o, s);
    }
}

extern "C" void kernel_launch(void* const* d_in, const int* in_sizes, int n_in,
                              void* d_out, int out_size, void* d_ws, size_t ws_size,
                              hipStream_t stream) {
    const float* x = (const float*)d_in[0];   // [256, 2048]
    const float* T = (const float*)d_in[1];   // [2048][2048] flattened
    float* out = (float*)d_out;               // [256, 2304]
    char* ws = (char*)d_ws;
    u16* Mh = (u16*)ws;
    u8*  Wt = (u8*)(ws + WT_BASE);
    u8*  Xb = (u8*)(ws + XB_BASE);

    k_prep<<<256, 256, 0, stream>>>(x, T, Wt, Xb);
    k_gemm<<<512, 512, 0, stream>>>(Xb, Wt, Mh, out);
    k_pair<<<512, 512, 0, stream>>>(Mh, x, out);
}

// Round 25
// 23.478 us; speedup vs baseline: 1.2609x; 1.2609x over previous
//
#include <hip/hip_runtime.h>
#include <math.h>

#define BATCH   256
#define IN_F    2048
#define OUT_F   256
#define NCOL    2048    /* OUT_F*KD */
#define OSTRIDE 2304    /* IN_F + OUT_F */
#define LOG2E   1.4426950408889634f

typedef float    f32x4  __attribute__((ext_vector_type(4)));
typedef _Float16 h16x2  __attribute__((ext_vector_type(2)));
typedef __fp16   fp16x2 __attribute__((ext_vector_type(2)));
typedef unsigned short u16;
typedef unsigned int   u32;
typedef unsigned char  u8;
typedef long long      i64;

// ws layout:
//   [0, 1MB)   Mh f16 [256 o][256 j][8 k]
//   [16,20MB)  Wt fp8 tiled [nt(128)][kc(256)][n16(16)][8]      (4 MB)
//   [24,24.5M) Xb fp8 tiled [rt(16)][kc(256)][r16(16)][8]*log2e (0.5 MB)
#define WT_BASE   (16u << 20)
#define XB_BASE   (24u << 20)

__device__ __forceinline__ float exp2_fast(float x) {
#if __has_builtin(__builtin_amdgcn_exp2f)
    return __builtin_amdgcn_exp2f(x);
#else
    float r; asm("v_exp_f32 %0, %1" : "=v"(r) : "v"(x)); return r;
#endif
}

__device__ __forceinline__ float hsum_neg(h16x2 s) {
#if __has_builtin(__builtin_amdgcn_fdot2)
    const h16x2 n1 = {(_Float16)-1.0f, (_Float16)-1.0f};
    return __builtin_amdgcn_fdot2(s, n1, 0.0f, false);
#else
    return -((float)s[0] + (float)s[1]);
#endif
}

__device__ __forceinline__ float bperm(int srcLane, float v) {
    return __builtin_bit_cast(float,
        __builtin_amdgcn_ds_bpermute(srcLane * 4, __builtin_bit_cast(int, v)));
}

// pack 4 f32 -> 4 fp8 e4m3 (RNE, OCP on gfx950) in one u32
__device__ __forceinline__ u32 pk4_fp8(float a, float b, float c, float d) {
    u32 r;
    asm("v_cvt_pk_fp8_f32 %0, %1, %2" : "=v"(r) : "v"(a), "v"(b));
    asm("v_cvt_pk_fp8_f32 %0, %1, %2 op_sel:[0,0,1]" : "+v"(r) : "v"(c), "v"(d));
    return r;
}

// ---------------------------------------------------------------------------
// Prep (256 blocks):
//   0..127   tconv -> Wt fp8, XCD-aligned with gemm consumers (C%8 == b%8)
//   128..255 xconv -> Xb fp8 (*log2e)
// ---------------------------------------------------------------------------
__global__ __launch_bounds__(256)
void k_prep(const float* __restrict__ X, const float* __restrict__ T,
            u8* __restrict__ Wt, u8* __restrict__ Xb) {
    const int b = blockIdx.x, t = threadIdx.x;
    if (b < 128) {
        const int c8 = b & 7;                  // XCD group
        const int kg = b >> 3;                 // 128-k group (0..15)
        const int p  = t & 127;                // col-pair index
        const int C  = c8 + 8 * (p >> 4);      // C-panel (C%8 == c8)
        const int n  = C * 32 + (p & 15) * 2;  // even column
        const int kh = (t >> 7) * 64;          // k-half within group
        const int nt = n >> 4, n16 = n & 15;
#pragma unroll
        for (int kc = 0; kc < 8; ++kc) {
            const int kb = kg * 128 + kh + kc * 8;
            float a0[8], a1[8];
#pragma unroll
            for (int r = 0; r < 8; ++r) {
                float2 v = *(const float2*)(T + (size_t)(kb + r) * NCOL + n);
                a0[r] = v.x;
                a1[r] = v.y;
            }
            uint2 p0 = {pk4_fp8(a0[0], a0[1], a0[2], a0[3]),
                        pk4_fp8(a0[4], a0[5], a0[6], a0[7])};
            uint2 p1 = {pk4_fp8(a1[0], a1[1], a1[2], a1[3]),
                        pk4_fp8(a1[4], a1[5], a1[6], a1[7])};
            u8* dst = Wt + ((size_t)(nt * 256 + (kb >> 3)) * 16 + n16) * 8;
            *(uint2*)dst       = p0;
            *(uint2*)(dst + 8) = p1;
        }
    } else {
        const int g   = b - 128;               // 0..127
        const int rt  = g >> 3;                // 0..15
        const int kcb = (g & 7) * 32;          // kc block (32 kc)
        const int r16 = t >> 4;                // 0..15
        const int kc  = kcb + (t & 15) * 2;    // kc pair
        const int row = rt * 16 + r16;
        const float* src = X + (size_t)row * IN_F + kc * 8;
        float v[16];
#pragma unroll
        for (int i = 0; i < 4; ++i)
            *(f32x4*)(v + i * 4) = *(const f32x4*)(src + i * 4);
        uint2 q0 = {pk4_fp8(v[0] * LOG2E, v[1] * LOG2E, v[2] * LOG2E, v[3] * LOG2E),
                    pk4_fp8(v[4] * LOG2E, v[5] * LOG2E, v[6] * LOG2E, v[7] * LOG2E)};
        uint2 q1 = {pk4_fp8(v[8] * LOG2E, v[9] * LOG2E, v[10] * LOG2E, v[11] * LOG2E),
                    pk4_fp8(v[12] * LOG2E, v[13] * LOG2E, v[14] * LOG2E, v[15] * LOG2E)};
        *(uint2*)(Xb + ((size_t)(rt * 256 + kc)     * 16 + r16) * 8) = q0;
        *(uint2*)(Xb + ((size_t)(rt * 256 + kc + 1) * 16 + r16) * 8) = q1;
    }
}

// ---------------------------------------------------------------------------
// MFMA GEMM fp8 (8-way in-block split-K). 512 blocks x 8 waves, 2 blocks/CU.
// bid%8 = C%8 matches the tconv writer XCD. A/B: 8 fp8/lane (i64 load).
// C/D frag: col = l&15, row = (l>>4)*4 + reg  [m89/m91].
// ---------------------------------------------------------------------------
__global__ __launch_bounds__(512, 4)
void k_gemm(const u8* __restrict__ Xb, const u8* __restrict__ Wt,
            u16* __restrict__ Mh) {
    __shared__ float L[8][32][33];     // 33.8 KB
    const int t = threadIdx.x, l = t & 63, kcw = t >> 6;
    const int bid = blockIdx.x;
    const int R = bid >> 6;            // 0..7
    const int C = bid & 63;            // 0..63

    const int lo = (l >> 4) * 128 + (l & 15) * 8;   // bytes
    const u8* ap0 = Xb + (size_t)(R * 2) * 32768 + kcw * 4096 + lo;
    const u8* ap1 = ap0 + 32768;
    const u8* bp0 = Wt + (size_t)(C * 2) * 32768 + kcw * 4096 + lo;
    const u8* bp1 = bp0 + 32768;

    f32x4 c00 = {0.f,0.f,0.f,0.f}, c01 = {0.f,0.f,0.f,0.f};
    f32x4 c10 = {0.f,0.f,0.f,0.f}, c11 = {0.f,0.f,0.f,0.f};

#pragma unroll 8
    for (int s = 0; s < 8; ++s) {
        i64 a0 = *(const i64*)(ap0 + s * 512);
        i64 a1 = *(const i64*)(ap1 + s * 512);
        i64 b0 = *(const i64*)(bp0 + s * 512);
        i64 b1 = *(const i64*)(bp1 + s * 512);
        c00 = __builtin_amdgcn_mfma_f32_16x16x32_fp8_fp8(a0, b0, c00, 0, 0, 0);
        c01 = __builtin_amdgcn_mfma_f32_16x16x32_fp8_fp8(a0, b1, c01, 0, 0, 0);
        c10 = __builtin_amdgcn_mfma_f32_16x16x32_fp8_fp8(a1, b0, c10, 0, 0, 0);
        c11 = __builtin_amdgcn_mfma_f32_16x16x32_fp8_fp8(a1, b1, c11, 0, 0, 0);
    }

    const int lq = l >> 4, lm = l & 15;
#define PUT(acc, qi, qj) do { \
        _Pragma("unroll") \
        for (int r = 0; r < 4; ++r) \
            L[kcw][(qj) * 16 + lm][(qi) * 16 + lq * 4 + r] = acc[r]; \
    } while (0)
    PUT(c00, 0, 0); PUT(c01, 0, 1); PUT(c10, 1, 0); PUT(c11, 1, 1);
#undef PUT
    __syncthreads();

    if (t < 256) {
        const int o2 = t >> 6;             // 0..3
        const int jl = (t & 63) >> 1;      // 0..31
        const int k0 = (t & 1) * 4;        // 0 or 4
        float v[4];
#pragma unroll
        for (int i = 0; i < 4; ++i) {
            const int c = o2 * 8 + k0 + i;
            float s0 = (L[0][c][jl] + L[1][c][jl]) + (L[2][c][jl] + L[3][c][jl]);
            float s1 = (L[4][c][jl] + L[5][c][jl]) + (L[6][c][jl] + L[7][c][jl]);
            v[i] = s0 + s1;
        }
        fp16x2 p0 = __builtin_amdgcn_cvt_pkrtz(v[0], v[1]);
        fp16x2 p1 = __builtin_amdgcn_cvt_pkrtz(v[2], v[3]);
        uint2 pk = {__builtin_bit_cast(u32, p0), __builtin_bit_cast(u32, p1)};
        *(uint2*)(Mh + ((size_t)(C * 4 + o2) * 256 + R * 32 + jl) * 8 + k0) = pk;
    }
}

// ---------------------------------------------------------------------------
// Pairwise L1-exp2 v4.1 (measured best): symmetric circulant, f32 credits
// via 4 ds_bpermute, fused x->out row copy, XCD-aligned o mapping.
// ---------------------------------------------------------------------------
__global__ __launch_bounds__(1024)
void k_pair(const u16* __restrict__ Mh, const float* __restrict__ X,
            float* __restrict__ out) {
    __shared__ __align__(16) uint4 Msh[BATCH];    // 4 KB
    __shared__ float Ps[16][256];                 // 16 KB
    const int t = threadIdx.x;
    const int g = blockIdx.x & 7, idx = blockIdx.x >> 3;
    const int o = (g + 8 * (idx >> 2)) * 4 + (idx & 3);   // (o>>2)%8 == g

    if (t < 256) Msh[t] = ((const uint4*)(Mh + (size_t)o * 2048))[t];

    {   // fused copy: row = blockIdx.x, 1024 threads x float2 = 8 KB
        const int row = blockIdx.x;
        *(float2*)(out + (size_t)row * OSTRIDE + t * 2) =
            *(const float2*)(X + (size_t)row * IN_F + t * 2);
    }
    __syncthreads();

    const int jg = t & 63, q = t >> 6;
    h16x2 m[4][4];
#pragma unroll
    for (int c = 0; c < 4; ++c) {
        uint4 mm = Msh[jg + 64 * c];
        m[c][0] = __builtin_bit_cast(h16x2, mm.x);
        m[c][1] = __builtin_bit_cast(h16x2, mm.y);
        m[c][2] = __builtin_bit_cast(h16x2, mm.z);
        m[c][3] = __builtin_bit_cast(h16x2, mm.w);
    }

    float acc[4] = {0.f, 0.f, 0.f, 0.f};
    const int dbase = q * 8 + 1;
#pragma unroll
    for (int ii = 0; ii < 8; ++ii) {
        const int d  = dbase + ii;
        const int dd = d & 63;
        const int dl = d >> 6;
        float e[4];
#pragma unroll
        for (int c = 0; c < 4; ++c) {
            uint4 uu = Msh[(jg + 64 * c + d) & 255];
            h16x2 d0 = __builtin_bit_cast(h16x2, uu.x) - m[c][0];
            h16x2 d1 = __builtin_bit_cast(h16x2, uu.y) - m[c][1];
            h16x2 d2 = __builtin_bit_cast(h16x2, uu.z) - m[c][2];
            h16x2 d3 = __builtin_bit_cast(h16x2, uu.w) - m[c][3];
            h16x2 e0 = __builtin_bit_cast(h16x2, __builtin_bit_cast(u32, d0) & 0x7fff7fffu);
            h16x2 e1 = __builtin_bit_cast(h16x2, __builtin_bit_cast(u32, d1) & 0x7fff7fffu);
            h16x2 e2 = __builtin_bit_cast(h16x2, __builtin_bit_cast(u32, d2) & 0x7fff7fffu);
            h16x2 e3 = __builtin_bit_cast(h16x2, __builtin_bit_cast(u32, d3) & 0x7fff7fffu);
            h16x2 s = (e0 + e1) + (e2 + e3);
            float ev = exp2_fast(hsum_neg(s));
            e[c] = ev;
            acc[c] += ev;
        }
        if (d != 128) {                           // wave-uniform branch
            const int src = (jg - dd) & 63;
            float r0 = bperm(src, e[0]);
            float r1 = bperm(src, e[1]);
            float r2 = bperm(src, e[2]);
            float r3 = bperm(src, e[3]);
            const int rot = dl + (jg < dd ? 1 : 0);   // 0..2
            acc[0] += rot == 0 ? r0 : (rot == 1 ? r3 : r2);
            acc[1] += rot == 0 ? r1 : (rot == 1 ? r0 : r3);
            acc[2] += rot == 0 ? r2 : (rot == 1 ? r1 : r0);
            acc[3] += rot == 0 ? r3 : (rot == 1 ? r2 : r1);
        }
    }
#pragma unroll
    for (int c = 0; c < 4; ++c) Ps[q][jg + 64 * c] = acc[c];
    __syncthreads();

    if (t < 256) {
        float s = 0.f;
#pragma unroll
        for (int q2 = 0; q2 < 16; ++q2) s += Ps[q2][t];
        out[(size_t)t * OSTRIDE + IN_F + o] = s;  // diagonal excluded: no -1
    }
}

extern "C" void kernel_launch(void* const* d_in, const int* in_sizes, int n_in,
                              void* d_out, int out_size, void* d_ws, size_t ws_size,
                              hipStream_t stream) {
    const float* x = (const float*)d_in[0];   // [256, 2048]
    const float* T = (const float*)d_in[1];   // [2048][2048] flattened
    float* out = (float*)d_out;               // [256, 2304]
    char* ws = (char*)d_ws;
    u16* Mh = (u16*)ws;
    u8*  Wt = (u8*)(ws + WT_BASE);
    u8*  Xb = (u8*)(ws + XB_BASE);

    k_prep<<<256, 256, 0, stream>>>(x, T, Wt, Xb);
    k_gemm<<<512, 512, 0, stream>>>(Xb, Wt, Mh);
    k_pair<<<256, 1024, 0, stream>>>(Mh, x, out);
}